// Round 20
// baseline (68.996 us; speedup 1.0000x reference)
//
#include <hip/hip_runtime.h>
#include <hip/hip_bf16.h>

#define N2 16384
#define D  128
#define PANEL 16384                       // bytes per 128x128 fp8 panel
#define SQC1 1.69864360258810896f         // sqrt(2*log2(e)), folded into zq
#define LN2  0.69314718055994530942f

typedef float f32x4 __attribute__((ext_vector_type(4)));

#if __has_builtin(__builtin_amdgcn_exp2f)
#define EXP2(x) __builtin_amdgcn_exp2f(x)
#else
#define EXP2(x) exp2f(x)
#endif

// f32 -> OCP e4m3fn, RNE. |f| <= ~1.8 here. (R8/R13-proven)
__device__ __forceinline__ unsigned char f2e4m3(float f) {
    union { float f; unsigned u; } v; v.f = f;
    unsigned s = (v.u >> 24) & 0x80;
    int e = (int)((v.u >> 23) & 255) - 127;
    unsigned m = v.u & 0x7fffff;
    if (e < -10) return (unsigned char)s;
    if (e >= -6) {
        unsigned r = m + 0x7ffff + ((m >> 20) & 1);
        unsigned mm = r >> 20;
        int E = e;
        if (mm >= 8) { mm = 0; E += 1; }
        return (unsigned char)(s | ((E + 7) << 3) | (mm & 7));
    }
    float a = fabsf(f) * 512.0f;
    int n = (int)rintf(a);
    return (unsigned char)(s | n);
}

// e4m3fn -> f32 (no NaN inputs produced by f2e4m3 here)
__device__ __forceinline__ float e4m3f(unsigned v) {
    unsigned s = v >> 7, e = (v >> 3) & 15, m = v & 7;
    float f;
    if (e) { union { unsigned u; float g; } x; x.u = ((e + 120) << 23) | (m << 20); f = x.g; }
    else   f = (float)m * 0.001953125f;   // m * 2^-9
    return s ? -f : f;
}

// stage one 16KB fp8 panel global->LDS via global_load_lds width=16 (4 ops).
// LDS dest linear; XOR swizzle pre-applied to the GLOBAL source (involution
// on 16B granules); reads use byte ^ ((row&7)<<4), row = byte>>7. (rule #21)
__device__ __forceinline__ void stage16(const char* __restrict__ g,
                                        char* lds, int tid) {
    const int wid = tid >> 6, lane = tid & 63;
    #pragma unroll
    for (int i = 0; i < 4; ++i) {
        int off = (wid << 12) + (i << 10) + (lane << 4);
        int src = off ^ (((off >> 7) & 7) << 4);
        __builtin_amdgcn_global_load_lds(
            (const __attribute__((address_space(1))) unsigned*)(g + src),
            (__attribute__((address_space(3))) unsigned*)(lds + (wid << 12) + (i << 10)),
            16, 0, 0);
    }
}

// ---------- kernel 1: L2-normalize -> fp8 sqrt(C1)*zn; zero rowsum/out ----------
__global__ void k_norm(const float* __restrict__ z, unsigned char* __restrict__ zq,
                       float* __restrict__ rowsum, float* __restrict__ out) {
    if (blockIdx.x < 64) rowsum[blockIdx.x * 256 + threadIdx.x] = 0.f;
    if (blockIdx.x == 64 && threadIdx.x == 0) out[0] = 0.f;
    int row  = blockIdx.x * 4 + (threadIdx.x >> 6);
    int lane = threadIdx.x & 63;
    const float2 v = ((const float2*)(z + (size_t)row * D))[lane];
    float ss = v.x * v.x + v.y * v.y;
    #pragma unroll
    for (int m = 1; m < 64; m <<= 1) ss += __shfl_xor(ss, m);
    float inv = SQC1 / fmaxf(sqrtf(ss), 1e-12f);
    unsigned short o = (unsigned short)f2e4m3(v.x * inv)
                     | ((unsigned short)f2e4m3(v.y * inv) << 8);
    ((unsigned short*)(zq + (size_t)row * D))[lane] = o;
}

// ---------- kernel 2: fp8 triple-buffer, stage-first, SINGLE barrier/tile ----------
// block (c, ti): s in [11c, ...); jt=(ti+s)&127. 48KB LDS -> 3 blocks/CU.
// iter t: { flush csp(t-1) [4 atomics]; stage B(t+1)->buf[(t+1)%3] [4 ops];
//           vmcnt(8) [drains stage(t), leaves flush+stage(t+1)]; barrier;
//           ds_read buf[t%3]; 64 MFMA; epilogue -> csp }.
// Race-freedom (d=3, L=1, stage BEFORE barrier): buf[(t+1)%3] was last read
// at iter t-2; every wave's t-2 reads completed before it reached
// barrier(t-1) (MFMAs consumed them), which all waves have passed.
// Uniform vmcnt(8) at every t incl. first/last (flush[4]+stage[4] newer).
__global__ __launch_bounds__(256, 3)
void k_sim(const unsigned char* __restrict__ zq, float* __restrict__ rowsum) {
    __shared__ char ls[3 * PANEL];        // 48KB triple buffer

    const int tileI = blockIdx.y;
    const int c = blockIdx.x;
    const int sLo = c * 11;
    const int nt = (c < 5) ? 11 : ((tileI < 64) ? 10 : 9);

    const int tid  = threadIdx.x;
    const int lane = tid & 63, wid = tid >> 6;
    const int wr = wid >> 1, wc = wid & 1;          // 2x2 waves: 64x64 each
    const int l16 = lane & 15, lg = lane >> 4;
    const char* zb = (const char*)zq;

    // prologue: A(ti) -> buf0, pull fp8 A fragments (32 VGPR) to registers
    stage16(zb + (size_t)tileI * PANEL, ls, tid);
    asm volatile("s_waitcnt vmcnt(0)" ::: "memory");
    __builtin_amdgcn_s_barrier();

    long af[4][4];                                     // [kk][m]
    #pragma unroll
    for (int kk = 0; kk < 4; ++kk)
        #pragma unroll
        for (int m = 0; m < 4; ++m) {
            int row = wr * 64 + m * 16 + l16;
            int d = row * 128 + kk * 32 + lg * 8;
            af[kk][m] = *(const long*)(ls + (d ^ ((row & 7) << 4)));
        }
    asm volatile("s_waitcnt lgkmcnt(0)" ::: "memory");
    __builtin_amdgcn_s_barrier();                      // buf0 free for B

    stage16(zb + (size_t)((tileI + sLo) & 127) * PANEL, ls, tid);   // B(0) -> buf0

    float rs[4][4];
    #pragma unroll
    for (int m = 0; m < 4; ++m)
        #pragma unroll
        for (int r = 0; r < 4; ++r) rs[m][r] = 0.f;
    float csp[4] = {0.f, 0.f, 0.f, 0.f};               // deferred col sums (reduced)
    int jtp = tileI;                                   // dummy first flush adds 0.0

    int cur = 0;                                       // t % 3
    for (int t = 0; t < nt; ++t) {
        const int s  = sLo + t;
        const int jt = (tileI + s) & 127;

        // a) flush previous tile's col sums (4 atomic VM ops, uniform)
        #pragma unroll
        for (int n = 0; n < 4; ++n)
            if (lg == 0)
                atomicAdd(&rowsum[jtp * 128 + wc * 64 + n * 16 + l16], csp[n]);
        // b) stage-first: B(t+1) -> buf[(t+1)%3]  (race-free, see header)
        if (t + 1 < nt) {
            int nxt = (cur == 2) ? 0 : cur + 1;
            stage16(zb + (size_t)((tileI + s + 1) & 127) * PANEL, ls + (nxt << 14), tid);
            // c) drain stage(t): 8 newer ops {flush[4], stage(t+1)[4]} in flight
            asm volatile("s_waitcnt vmcnt(8)" ::: "memory");
        } else {
            asm volatile("s_waitcnt vmcnt(4)" ::: "memory");  // only flush[4] newer
        }
        __builtin_amdgcn_s_barrier();                  // the ONLY barrier per tile

        const char* rbuf = ls + (cur << 14);

        // d) K-loop: per-kk B frags (8 transient regs), 16 MFMA each
        f32x4 acc[4][4];
        #pragma unroll
        for (int kk = 0; kk < 4; ++kk) {
            long bk[4];
            #pragma unroll
            for (int n = 0; n < 4; ++n) {
                int row = wc * 64 + n * 16 + l16;
                int d = row * 128 + kk * 32 + lg * 8;
                bk[n] = *(const long*)(rbuf + (d ^ ((row & 7) << 4)));
            }
            #pragma unroll
            for (int m = 0; m < 4; ++m)
                #pragma unroll
                for (int n = 0; n < 4; ++n)
                    acc[m][n] = __builtin_amdgcn_mfma_f32_16x16x32_fp8_fp8(
                        af[kk][m], bk[n],
                        (kk == 0) ? f32x4{0.f, 0.f, 0.f, 0.f} : acc[m][n], 0, 0, 0);
        }

        // e) epilogue: e = exp2(acc) = exp(sim); col sums -> csp (deferred)
        if (s == 0) {
            // diagonal tile: mask self-sim, row sums only; csp stays 0
            #pragma unroll
            for (int m = 0; m < 4; ++m)
                #pragma unroll
                for (int r = 0; r < 4; ++r) {
                    int li = wr * 64 + m * 16 + lg * 4 + r;
                    float a = 0.f;
                    #pragma unroll
                    for (int n = 0; n < 4; ++n) {
                        int lj = wc * 64 + n * 16 + l16;
                        float e = EXP2(acc[m][n][r]);
                        a += (li == lj) ? 0.f : e;
                    }
                    rs[m][r] += a;
                }
            csp[0] = csp[1] = csp[2] = csp[3] = 0.f;
        } else {
            float cs[4] = {0.f, 0.f, 0.f, 0.f};
            #pragma unroll
            for (int m = 0; m < 4; ++m)
                #pragma unroll
                for (int r = 0; r < 4; ++r) {
                    float a = 0.f;
                    #pragma unroll
                    for (int n = 0; n < 4; ++n) {
                        float e = EXP2(acc[m][n][r]);
                        a += e;
                        cs[n] += e;
                    }
                    rs[m][r] += a;
                }
            #pragma unroll
            for (int n = 0; n < 4; ++n) {
                float v = cs[n];
                v += __shfl_xor(v, 16);
                v += __shfl_xor(v, 32);
                csp[n] = v;
            }
        }
        jtp = jt;
        cur = (cur == 2) ? 0 : cur + 1;
    }

    // trailing flush: last tile's col sums
    #pragma unroll
    for (int n = 0; n < 4; ++n)
        if (lg == 0)
            atomicAdd(&rowsum[jtp * 128 + wc * 64 + n * 16 + l16], csp[n]);

    // row-sum flush: reduce across 16 column-lanes, one atomic per row
    #pragma unroll
    for (int m = 0; m < 4; ++m)
        #pragma unroll
        for (int r = 0; r < 4; ++r) {
            float v = rs[m][r];
            v += __shfl_xor(v, 1);
            v += __shfl_xor(v, 2);
            v += __shfl_xor(v, 4);
            v += __shfl_xor(v, 8);
            if (l16 == 0)
                atomicAdd(&rowsum[tileI * 128 + wr * 64 + m * 16 + lg * 4 + r], v);
        }
}

// ---------- kernel 3: fused loss + mean (fp8 pos-dot, R13-verbatim) ----------
// mean loss = (1/N2) * [ sum_i ln(rowsum_i) - ln2 * sum_{i,k} zq[i][k]*zq[i^1][k] ]
__global__ void k_loss_reduce(const unsigned char* __restrict__ zq,
                              const float* __restrict__ rowsum,
                              float* __restrict__ out) {
    const int tid = threadIdx.x + blockIdx.x * 256;   // 64 blocks x 256 = 16384
    float p = 0.f;
    const uint4* v16 = (const uint4*)zq;              // 16 fp8 per uint4
    for (int v = tid; v < N2 * D / 16; v += 64 * 256) {
        uint4 a = v16[v];
        uint4 b = v16[v ^ 8];                         // partner row i^1, same k-slice
        const unsigned* aw = (const unsigned*)&a;
        const unsigned* bw = (const unsigned*)&b;
        #pragma unroll
        for (int w = 0; w < 4; ++w)
            #pragma unroll
            for (int j = 0; j < 4; ++j)
                p += e4m3f((aw[w] >> (8 * j)) & 255) * e4m3f((bw[w] >> (8 * j)) & 255);
    }
    float part = logf(rowsum[tid]) - LN2 * p;         // exactly one row per thread

    __shared__ float sm[4];
    #pragma unroll
    for (int m = 1; m < 64; m <<= 1) part += __shfl_xor(part, m);
    if ((threadIdx.x & 63) == 0) sm[threadIdx.x >> 6] = part;
    __syncthreads();
    if (threadIdx.x == 0)
        atomicAdd(out, (sm[0] + sm[1] + sm[2] + sm[3]) * (1.0f / (float)N2));
}

extern "C" void kernel_launch(void* const* d_in, const int* in_sizes, int n_in,
                              void* d_out, int out_size, void* d_ws, size_t ws_size,
                              hipStream_t stream) {
    const float* z = (const float*)d_in[0];
    float* out = (float*)d_out;

    unsigned char* zq = (unsigned char*)d_ws;                         // 2 MiB fp8
    float* rowsum = (float*)((char*)d_ws + (size_t)N2 * D);           // 64 KiB

    k_norm<<<N2 / 4, 256, 0, stream>>>(z, zq, rowsum, out);
    dim3 grid(6, 128);                                                // s-chunks x i-tiles
    k_sim<<<grid, 256, 0, stream>>>(zq, rowsum);
    k_loss_reduce<<<64, 256, 0, stream>>>(zq, rowsum, out);
}

// Round 21
// 62.458 us; speedup vs baseline: 1.1047x; 1.1047x over previous
//
#include <hip/hip_runtime.h>
#include <hip/hip_bf16.h>

#define N2 16384
#define D  128
#define PANEL 32768                       // bytes per 128x128 bf16 panel
#define SQC1 1.69864360258810896f         // sqrt(2*log2(e)), folded into zn
#define LN2  0.69314718055994530942f

typedef __bf16 bf16x8 __attribute__((ext_vector_type(8)));
typedef float  f32x4  __attribute__((ext_vector_type(4)));

#if __has_builtin(__builtin_amdgcn_exp2f)
#define EXP2(x) __builtin_amdgcn_exp2f(x)
#else
#define EXP2(x) exp2f(x)
#endif

__device__ __forceinline__ unsigned short f2bf(float f) {
    union { float f; unsigned u; } v; v.f = f;
    unsigned r = v.u + 0x7fffu + ((v.u >> 16) & 1u);
    return (unsigned short)(r >> 16);
}

// stage one 32KB panel global->LDS via global_load_lds width=16.
// LDS dest linear; XOR swizzle on the GLOBAL source (involution); reads
// use byte ^ ((row&7)<<4). (rule #21)
__device__ __forceinline__ void stage_panel(const char* __restrict__ g,
                                            char* lds, int tid) {
    const int wid = tid >> 6, lane = tid & 63;
    #pragma unroll
    for (int i = 0; i < 8; ++i) {
        int off = (wid << 13) + (i << 10) + (lane << 4);
        int src = off ^ (((off >> 8) & 7) << 4);
        __builtin_amdgcn_global_load_lds(
            (const __attribute__((address_space(1))) unsigned*)(g + src),
            (__attribute__((address_space(3))) unsigned*)(lds + (wid << 13) + (i << 10)),
            16, 0, 0);
    }
}

// ---------- kernel 1: L2-normalize -> bf16 sqrt(C1)*zn; pos-dot in fp32 ----------
// Block handles rows 4b..4b+3; partner row r^1 is always in-block (wid^1).
// Normalized fp32 values exchanged via LDS -> per-block pos partial written
// unconditionally to posparts[bid] (no zeroing, no atomics). Also zeroes
// rowsum slices and out.
__global__ void k_norm(const float* __restrict__ z, unsigned short* __restrict__ zn,
                       float* __restrict__ rowsum, float* __restrict__ posparts,
                       float* __restrict__ out) {
    __shared__ float xs[4][64][2];        // 2KB: normalized fp32 exchange
    __shared__ float ps[4];
    if (blockIdx.x < 64) rowsum[blockIdx.x * 256 + threadIdx.x] = 0.f;
    if (blockIdx.x == 64 && threadIdx.x == 0) out[0] = 0.f;
    int wid  = threadIdx.x >> 6, lane = threadIdx.x & 63;
    int row  = blockIdx.x * 4 + wid;
    const float2 v = ((const float2*)(z + (size_t)row * D))[lane];
    float ss = v.x * v.x + v.y * v.y;
    #pragma unroll
    for (int m = 1; m < 64; m <<= 1) ss += __shfl_xor(ss, m);
    float inv = SQC1 / fmaxf(sqrtf(ss), 1e-12f);
    float nx = v.x * inv, ny = v.y * inv;
    ushort2 o; o.x = f2bf(nx); o.y = f2bf(ny);
    ((ushort2*)(zn + (size_t)row * D))[lane] = o;

    // pos-dot with partner row (r^1 = wid^1 in this block), fp32
    xs[wid][lane][0] = nx; xs[wid][lane][1] = ny;
    __syncthreads();
    float d = nx * xs[wid ^ 1][lane][0] + ny * xs[wid ^ 1][lane][1];
    #pragma unroll
    for (int m = 1; m < 64; m <<= 1) d += __shfl_xor(d, m);
    if (lane == 0) ps[wid] = d;
    __syncthreads();
    if (threadIdx.x == 0)
        posparts[blockIdx.x] = ps[0] + ps[1] + ps[2] + ps[3];   // sum of folded dots
}

// ---------- kernel 2: R17's symmetric fused sim GEMM (52us-verified, verbatim) ----------
// block (c, ti): s in [16c, 16c+16) (+s=64 for c==3, ti<64). jt=(ti+s)&127.
__global__ __launch_bounds__(256, 2)
void k_sim(const unsigned short* __restrict__ zn, float* __restrict__ rowsum) {
    __shared__ unsigned short ls[2][PANEL / 2];
    char* ls0 = (char*)&ls[0][0];
    char* ls1 = (char*)&ls[1][0];

    const int tileI = blockIdx.y;
    const int sBase = blockIdx.x * 16;
    const int nt = (blockIdx.x == 3 && tileI < 64) ? 17 : 16;
    const int tid  = threadIdx.x;
    const int lane = tid & 63, wid = tid >> 6;
    const int wr = wid >> 1, wc = wid & 1;          // 2x2 wave grid, 64x64 each
    const int l16 = lane & 15, lg = lane >> 4;
    const char* znb = (const char*)zn;
    const f32x4 ZERO = {0.f, 0.f, 0.f, 0.f};

    // prologue: stage A(ti) -> ls0, B(s=sBase) -> ls1
    stage_panel(znb + (size_t)tileI * PANEL, ls0, tid);
    stage_panel(znb + (size_t)((tileI + sBase) & 127) * PANEL, ls1, tid);
    asm volatile("s_waitcnt vmcnt(8)" ::: "memory");   // A landed
    __builtin_amdgcn_s_barrier();

    // A fragments -> registers (reused for all tiles)
    bf16x8 af[4][4];                                   // [kk][m]
    #pragma unroll
    for (int kk = 0; kk < 4; ++kk)
        #pragma unroll
        for (int m = 0; m < 4; ++m) {
            int row = wr * 64 + m * 16 + l16;
            int d = row * 256 + kk * 64 + lg * 16;
            af[kk][m] = *(const bf16x8*)(ls0 + (d ^ ((row & 7) << 4)));
        }
    asm volatile("s_waitcnt lgkmcnt(0)" ::: "memory");
    __builtin_amdgcn_s_barrier();                      // ls0 now reusable

    float rs[4][4];
    #pragma unroll
    for (int m = 0; m < 4; ++m)
        #pragma unroll
        for (int r = 0; r < 4; ++r) rs[m][r] = 0.f;

    for (int t = 0; t < nt; ++t) {
        const int s  = sBase + t;
        const int jt = (tileI + s) & 127;
        char* rbuf = (t & 1) ? ls0 : ls1;              // B(s)
        char* sbuf = (t & 1) ? ls1 : ls0;              // B(s+1) dest
        if (t < nt - 1) {
            stage_panel(znb + (size_t)((tileI + s + 1) & 127) * PANEL, sbuf, tid);
            asm volatile("s_waitcnt vmcnt(8)" ::: "memory");  // B(s) landed
        } else {
            asm volatile("s_waitcnt vmcnt(0)" ::: "memory");
        }
        __builtin_amdgcn_s_barrier();

        bf16x8 bfr[4][4];                              // [kk][n]
        #pragma unroll
        for (int kk = 0; kk < 4; ++kk)
            #pragma unroll
            for (int n = 0; n < 4; ++n) {
                int row = wc * 64 + n * 16 + l16;
                int d = row * 256 + kk * 64 + lg * 16;
                bfr[kk][n] = *(const bf16x8*)(rbuf + (d ^ ((row & 7) << 4)));
            }
        asm volatile("s_waitcnt lgkmcnt(0)" ::: "memory");
        __builtin_amdgcn_s_barrier();                  // rbuf free for next stage

        f32x4 acc[4][4];
        #pragma unroll
        for (int m = 0; m < 4; ++m)
            #pragma unroll
            for (int n = 0; n < 4; ++n)
                acc[m][n] = __builtin_amdgcn_mfma_f32_16x16x32_bf16(af[0][m], bfr[0][n], ZERO, 0, 0, 0);
        #pragma unroll
        for (int kk = 1; kk < 4; ++kk)
            #pragma unroll
            for (int m = 0; m < 4; ++m)
                #pragma unroll
                for (int n = 0; n < 4; ++n)
                    acc[m][n] = __builtin_amdgcn_mfma_f32_16x16x32_bf16(af[kk][m], bfr[kk][n], acc[m][n], 0, 0, 0);

        // epilogue: e = exp2(acc) = exp(sim); rows accumulate in regs,
        // cols flushed per tile (jt changes every tile).
        if (s == 0) {
            // diagonal tile: mask self-sim, row sums only
            #pragma unroll
            for (int m = 0; m < 4; ++m)
                #pragma unroll
                for (int r = 0; r < 4; ++r) {
                    int li = wr * 64 + m * 16 + lg * 4 + r;
                    float a = 0.f;
                    #pragma unroll
                    for (int n = 0; n < 4; ++n) {
                        int lj = wc * 64 + n * 16 + l16;
                        float e = EXP2(acc[m][n][r]);
                        a += (li == lj) ? 0.f : e;
                    }
                    rs[m][r] += a;
                }
        } else {
            float cs[4] = {0.f, 0.f, 0.f, 0.f};
            #pragma unroll
            for (int m = 0; m < 4; ++m)
                #pragma unroll
                for (int r = 0; r < 4; ++r) {
                    float a = 0.f;
                    #pragma unroll
                    for (int n = 0; n < 4; ++n) {
                        float e = EXP2(acc[m][n][r]);
                        a += e;
                        cs[n] += e;
                    }
                    rs[m][r] += a;
                }
            // column flush: reduce over the 4 lg row-groups of this wave
            #pragma unroll
            for (int n = 0; n < 4; ++n) {
                float v = cs[n];
                v += __shfl_xor(v, 16);
                v += __shfl_xor(v, 32);
                if (lg == 0)
                    atomicAdd(&rowsum[jt * 128 + wc * 64 + n * 16 + l16], v);
            }
        }
    }

    // final: row sums -> reduce across 16 column-lanes, one atomic/row
    #pragma unroll
    for (int m = 0; m < 4; ++m)
        #pragma unroll
        for (int r = 0; r < 4; ++r) {
            float v = rs[m][r];
            v += __shfl_xor(v, 1);
            v += __shfl_xor(v, 2);
            v += __shfl_xor(v, 4);
            v += __shfl_xor(v, 8);
            if (l16 == 0)
                atomicAdd(&rowsum[tileI * 128 + wr * 64 + m * 16 + lg * 4 + r], v);
        }
}

// ---------- kernel 3: loss mean from rowsum + posparts only ----------
// mean loss = (1/N2) * [ sum_i ln(rowsum_i) - ln2 * sum_b posparts_b ]
__global__ void k_loss_reduce(const float* __restrict__ rowsum,
                              const float* __restrict__ posparts,
                              float* __restrict__ out) {
    const int tid = threadIdx.x + blockIdx.x * 256;   // 64 blocks x 256 = 16384
    float part = logf(rowsum[tid]);
    if (blockIdx.x == 0) {                            // fold pos partials (4096)
        float pp = 0.f;
        for (int i = threadIdx.x; i < N2 / 4; i += 256) pp += posparts[i];
        part -= LN2 * pp;
    }
    __shared__ float sm[4];
    #pragma unroll
    for (int m = 1; m < 64; m <<= 1) part += __shfl_xor(part, m);
    if ((threadIdx.x & 63) == 0) sm[threadIdx.x >> 6] = part;
    __syncthreads();
    if (threadIdx.x == 0)
        atomicAdd(out, (sm[0] + sm[1] + sm[2] + sm[3]) * (1.0f / (float)N2));
}

extern "C" void kernel_launch(void* const* d_in, const int* in_sizes, int n_in,
                              void* d_out, int out_size, void* d_ws, size_t ws_size,
                              hipStream_t stream) {
    const float* z = (const float*)d_in[0];
    float* out = (float*)d_out;

    unsigned short* zn = (unsigned short*)d_ws;                       // 4 MiB
    float* rowsum   = (float*)((char*)d_ws + (size_t)N2 * D * 2);     // 64 KiB
    float* posparts = rowsum + N2;                                    // 16 KiB

    k_norm<<<N2 / 4, 256, 0, stream>>>(z, zn, rowsum, posparts, out);
    dim3 grid(4, 128);                                                // s-chunks x i-tiles
    k_sim<<<grid, 256, 0, stream>>>(zn, rowsum);
    k_loss_reduce<<<64, 256, 0, stream>>>(rowsum, posparts, out);
}